// Round 1
// baseline (146.517 us; speedup 1.0000x reference)
//
#include <hip/hip_runtime.h>

#define B_N 32
#define LQ  1024
#define LK  1024
#define DH  128

typedef __attribute__((ext_vector_type(4))) float    f32x4;
typedef __attribute__((ext_vector_type(8))) short    s16x8;
typedef __attribute__((ext_vector_type(4))) _Float16 f16x4;
typedef __attribute__((ext_vector_type(8))) _Float16 f16x8;

// fp32 -> bf16 round-to-nearest-even
__device__ inline unsigned short f2bf(float f) {
    union { float f; unsigned u; } c; c.f = f;
    unsigned u = c.u;
    u += 0x7fffu + ((u >> 16) & 1u);
    return (unsigned short)(u >> 16);
}

// logit2 = score * (1/sqrt(128)) * log2(e)
#define ESCALE 0.12751743f

// ---------------------------------------------------------------------------
// Prepass with vl-aware skip (~46% of tiles never read by attn).
// blocks 0..1023: K tiles -> Kb bf16 fragments for QK^T (16x16x32). Needed
//   only for kt < 2*nch and vl>0 (vl==0: K values are masked everywhere).
// blocks 1024..2047: V tiles -> Vt f16 fragment-PAIRS for PV (16x16x16).
//   Needed for kt < 2*nch with nch=16 when vl==0 (P==1 -> O = mean(V)).
// Attn never touches fragments past nch chunks, so skipped tiles may hold
// harness poison (and for vl==0 the Kb poison feeds exp2 -> finite -> then
// overwritten by emaskval; no NaN path).
// ---------------------------------------------------------------------------
__global__ __launch_bounds__(256)
void prep_kv(const float* __restrict__ K, const float* __restrict__ V,
             const int* __restrict__ VL,
             unsigned short* __restrict__ Kb, _Float16* __restrict__ Vt)
{
    __shared__ float tl[32 * 132];
    const int tid  = threadIdx.x;
    const int lane = tid & 63;
    const int wv   = tid >> 6;
    const int n    = lane & 15;
    const int quad = lane >> 4;

    const bool isK = blockIdx.x < 1024;
    const int  t   = isK ? blockIdx.x : (blockIdx.x - 1024);
    const int  b   = t >> 5, kt = t & 31;

    const int vl = VL[b];
    if (isK) {
        if (vl <= 0 || kt >= 2 * ((vl + 63) >> 6)) return;   // block-uniform
    } else {
        const int nch = (vl > 0) ? ((vl + 63) >> 6) : 16;
        if (kt >= 2 * nch) return;                           // block-uniform
    }

    const float4* src = (const float4*)((isK ? K : V) + ((size_t)b * LK + kt * 32) * DH);
    #pragma unroll
    for (int h = 0; h < 4; ++h) {
        const int idx = h * 256 + tid;
        const int row = idx >> 5, c4 = idx & 31;
        *(float4*)&tl[row * 132 + c4 * 4] = src[idx];
    }
    __syncthreads();

    if (isK) {
        union { s16x8 v; unsigned short u[8]; } t8;
        #pragma unroll
        for (int h = 0; h < 2; ++h) {
            const int f = wv * 2 + h;
            const int tt2 = f >> 2, s = f & 3;
            const float* p = &tl[(tt2 * 16 + n) * 132 + s * 32 + quad * 8];
            const float4 a = *(const float4*)p;
            const float4 c = *(const float4*)(p + 4);
            t8.u[0] = f2bf(a.x); t8.u[1] = f2bf(a.y); t8.u[2] = f2bf(a.z); t8.u[3] = f2bf(a.w);
            t8.u[4] = f2bf(c.x); t8.u[5] = f2bf(c.y); t8.u[6] = f2bf(c.z); t8.u[7] = f2bf(c.w);
            const int w = b * 256 + (kt * 2 + tt2) * 4 + s;
            *(s16x8*)(Kb + (size_t)w * 512 + lane * 8) = t8.v;
        }
    } else {
        #pragma unroll
        for (int h = 0; h < 2; ++h) {
            const int f  = wv * 2 + h;
            const int kg = f >> 2, dp = f & 3;
            f16x8 t8;
            #pragma unroll
            for (int i = 0; i < 4; ++i) {
                const float* row = &tl[(kg * 16 + quad * 4 + i) * 132 + dp * 32 + n];
                t8[i]     = (_Float16)row[0];
                t8[4 + i] = (_Float16)row[16];
            }
            const int v = (b * 64 + kt * 2 + kg) * 4 + dp;
            *(f16x8*)(Vt + (size_t)v * 512 + lane * 8) = t8;
        }
    }
}

// ---------------------------------------------------------------------------
// Attention, occupancy-split version.
// OLD: 2 waves/block, each wave = 2 qtiles (32 rows) + 2-way split-K.
//      ~160 VGPR/wave -> waves_per_eu(2,2) -> 2 waves/SIMD -> latency-bound
//      (32 global dwordx4 loads/chunk + 4-deep MFMA chains barely covered).
// NEW: 4 waves/block (256 thr). wave w: h = w>>1 (qtile, 16 q-rows),
//      s0 = w&1 (split-K parity, chunks s0, s0+2, ...). Per-wave state:
//      o[8] f32x4 (32 VGPR) + qf[4] (16) + pA[4] (8) ~ 100 VGPR ->
//      waves_per_eu(4,4) -> 4 waves/SIMD, 16 waves/CU. Chunk assignment and
//      accumulation order identical to old kernel -> bitwise-same numerics.
// K/V fragment loads are duplicated across the h-wave pair; they hit L1/L2
// (per-batch Kb+Vt = 512 KB, XCD-affine via block swizzle).
// Register rule (r6-r8 failure): NEVER index an accumulator array with a
// runtime value — all register indices below are compile-time constants.
// Block swizzle: b's low 3 bits = blockIdx&7 (XCD affinity: 4 batches/XCD,
// ~1 MB working set in L2), b's top 2 bits mix in (idx>>3)+(idx>>8) so the
// stride-256 CU family {c, c+256, c+512, c+768} gets 4 DIFFERENT batches.
// Bijective per 32-block group.
// Transposed-S trick: S^T = K·Q^T C-layout (row=kpos=quad*4+i, col=qrow)
// == A-operand layout of 16x16x16 f16 MFMA -> exp2(S^T) feeds PV directly.
// ---------------------------------------------------------------------------
__global__ __launch_bounds__(256)
__attribute__((amdgpu_waves_per_eu(4, 4)))
void attn_fwd(const float* __restrict__ Q, const unsigned short* __restrict__ Kb,
              const _Float16* __restrict__ Vt, const int* __restrict__ VL,
              float* __restrict__ O)
{
    __shared__ f32x4 Om[2][8][64];
    __shared__ float Lm[2][64];

    const int tid  = threadIdx.x;
    const int lane = tid & 63;
    const int w    = tid >> 6;
    const int h    = w >> 1;      // qtile (16 q-rows)
    const int s0   = w & 1;       // split-K parity
    const int quad = lane >> 4;
    const int m16  = lane & 15;

    const int idx = blockIdx.x;
    const int qg  = idx >> 5;
    const int b   = (idx & 7) | ((((idx >> 3) + (idx >> 8)) & 3) << 3);
    const int q0  = qg * 32;

    const int vl = VL[b];
    const int nch = (vl > 0) ? ((vl + 63) >> 6) : 16;
    const float emaskval = (vl == 0) ? 1.0f : 0.0f;

    // Q fragments for this wave's single qrow-tile (B-operand of S^T MFMA)
    s16x8 qf[4];
    {
        const float* qrow = Q + ((size_t)b * LQ + q0 + h * 16 + m16) * DH + quad * 8;
        #pragma unroll
        for (int s = 0; s < 4; ++s) {
            const float4 a = *(const float4*)(qrow + s * 32);
            const float4 c = *(const float4*)(qrow + s * 32 + 4);
            union { s16x8 v; unsigned short u[8]; } t;
            t.u[0] = f2bf(a.x); t.u[1] = f2bf(a.y); t.u[2] = f2bf(a.z); t.u[3] = f2bf(a.w);
            t.u[4] = f2bf(c.x); t.u[5] = f2bf(c.y); t.u[6] = f2bf(c.z); t.u[7] = f2bf(c.w);
            qf[s] = t.v;
        }
    }

    f32x4 o[8];
    #pragma unroll
    for (int dt = 0; dt < 8; ++dt) o[dt] = (f32x4){0.f, 0.f, 0.f, 0.f};
    float lrun = 0.f;

    const unsigned short* kbase = Kb + (size_t)b * (256 * 512) + lane * 8;
    const _Float16*       vbase = Vt + (size_t)b * (256 * 512) + lane * 8;

    for (int kb = s0; kb < nch; kb += 2) {
        const bool maskc = (kb * 64 + 64 > vl);
        f16x4 pA[4];

        // ---- S^T = K Q^T per 16-kpos tile g, softmaxed immediately ----
        #pragma unroll
        for (int g = 0; g < 4; ++g) {
            const unsigned short* kc = kbase + (size_t)((kb * 4 + g) * 4) * 512;
            f32x4 st = (f32x4){0.f, 0.f, 0.f, 0.f};
            #pragma unroll
            for (int s = 0; s < 4; ++s) {
                const s16x8 kf = *(const s16x8*)(kc + s * 512);
                st = __builtin_amdgcn_mfma_f32_16x16x32_bf16(kf, qf[s], st, 0, 0, 0);
            }
            #pragma unroll
            for (int i = 0; i < 4; ++i) {
                float e = __builtin_amdgcn_exp2f(st[i] * ESCALE);
                if (maskc && (kb * 64 + g * 16 + quad * 4 + i >= vl)) e = emaskval;
                lrun += e;
                pA[g][i] = (_Float16)e;
            }
        }

        // ---- O += P V : 4 kpos-tiles x 4 d-pairs ----
        #pragma unroll
        for (int g = 0; g < 4; ++g) {
            const _Float16* vc = vbase + (size_t)((kb * 4 + g) * 4) * 512;
            #pragma unroll
            for (int dp = 0; dp < 4; ++dp) {
                const f16x8 wv8 = *(const f16x8*)(vc + dp * 512);
                const f16x4 lo  = __builtin_shufflevector(wv8, wv8, 0, 1, 2, 3);
                const f16x4 hi  = __builtin_shufflevector(wv8, wv8, 4, 5, 6, 7);
                o[dp * 2]     = __builtin_amdgcn_mfma_f32_16x16x16f16(pA[g], lo, o[dp * 2],     0, 0, 0);
                o[dp * 2 + 1] = __builtin_amdgcn_mfma_f32_16x16x16f16(pA[g], hi, o[dp * 2 + 1], 0, 0, 0);
            }
        }
    }

    // ---- split-K merge across the s-wave pair (per qtile h) ----
    if (s0 == 1) {
        #pragma unroll
        for (int dt = 0; dt < 8; ++dt) Om[h][dt][lane] = o[dt];
        Lm[h][lane] = lrun;
    }
    __syncthreads();
    if (s0 == 0) {
        f32x4 om[8];
        #pragma unroll
        for (int dt = 0; dt < 8; ++dt) om[dt] = o[dt] + Om[h][dt][lane];
        float L = lrun + Lm[h][lane];

        // L[qrow=m16] total across quads, then per-row 1/L via shfl
        L += __shfl_xor(L, 16);
        L += __shfl_xor(L, 32);
        const size_t obase = ((size_t)b * LQ + q0 + h * 16 + quad * 4) * DH + m16;
        #pragma unroll
        for (int r = 0; r < 4; ++r) {
            const float inv = 1.0f / __shfl(L, quad * 4 + r);
            #pragma unroll
            for (int dt = 0; dt < 8; ++dt)
                O[obase + (size_t)r * DH + dt * 16] = om[dt][r] * inv;
        }
    }
}

extern "C" void kernel_launch(void* const* d_in, const int* in_sizes, int n_in,
                              void* d_out, int out_size, void* d_ws, size_t ws_size,
                              hipStream_t stream) {
    const float* Q  = (const float*)d_in[0];
    const float* K  = (const float*)d_in[1];
    const float* V  = (const float*)d_in[2];
    const int*   VL = (const int*)d_in[3];
    float* O = (float*)d_out;
    (void)in_sizes; (void)n_in; (void)out_size; (void)ws_size;

    unsigned short* Kb = (unsigned short*)d_ws;                      // 8 MB K fragments
    _Float16*       Vt = (_Float16*)(Kb + (size_t)B_N * 256 * 512);  // 8 MB V frag-pairs

    prep_kv<<<dim3(2048), dim3(256), 0, stream>>>(K, V, VL, Kb, Vt);
    attn_fwd<<<dim3(B_N * (LQ / 32)), dim3(256), 0, stream>>>(Q, Kb, Vt, VL, O);
}

// Round 2
// 115.849 us; speedup vs baseline: 1.2647x; 1.2647x over previous
//
#include <hip/hip_runtime.h>

#define B_N 32
#define LQ  1024
#define LK  1024
#define DH  128

typedef __attribute__((ext_vector_type(4))) float    f32x4;
typedef __attribute__((ext_vector_type(8))) short    s16x8;
typedef __attribute__((ext_vector_type(4))) _Float16 f16x4;
typedef __attribute__((ext_vector_type(8))) _Float16 f16x8;

// fp32 -> bf16 round-to-nearest-even
__device__ inline unsigned short f2bf(float f) {
    union { float f; unsigned u; } c; c.f = f;
    unsigned u = c.u;
    u += 0x7fffu + ((u >> 16) & 1u);
    return (unsigned short)(u >> 16);
}

// logit2 = score * (1/sqrt(128)) * log2(e)
#define ESCALE 0.12751743f

// async global->LDS, 16B per lane (dest must be wave-uniform base + lane*16)
#define G2L16(gp, lp) __builtin_amdgcn_global_load_lds(                         \
    (const __attribute__((address_space(1))) void*)(gp),                        \
    (__attribute__((address_space(3))) void*)(lp), 16, 0, 0)

// ---------------------------------------------------------------------------
// Prepass with vl-aware skip (~46% of tiles never read by attn). UNCHANGED
// from the 117.5us version (byte-identical Kb/Vt layout + skip logic).
// blocks 0..1023: K tiles -> Kb bf16 fragments for QK^T (16x16x32).
// blocks 1024..2047: V tiles -> Vt f16 fragment-PAIRS for PV (16x16x16).
// ---------------------------------------------------------------------------
__global__ __launch_bounds__(256)
void prep_kv(const float* __restrict__ K, const float* __restrict__ V,
             const int* __restrict__ VL,
             unsigned short* __restrict__ Kb, _Float16* __restrict__ Vt)
{
    __shared__ float tl[32 * 132];
    const int tid  = threadIdx.x;
    const int lane = tid & 63;
    const int wv   = tid >> 6;
    const int n    = lane & 15;
    const int quad = lane >> 4;

    const bool isK = blockIdx.x < 1024;
    const int  t   = isK ? blockIdx.x : (blockIdx.x - 1024);
    const int  b   = t >> 5, kt = t & 31;

    const int vl = VL[b];
    if (isK) {
        if (vl <= 0 || kt >= 2 * ((vl + 63) >> 6)) return;   // block-uniform
    } else {
        const int nch = (vl > 0) ? ((vl + 63) >> 6) : 16;
        if (kt >= 2 * nch) return;                           // block-uniform
    }

    const float4* src = (const float4*)((isK ? K : V) + ((size_t)b * LK + kt * 32) * DH);
    #pragma unroll
    for (int h = 0; h < 4; ++h) {
        const int idx = h * 256 + tid;
        const int row = idx >> 5, c4 = idx & 31;
        *(float4*)&tl[row * 132 + c4 * 4] = src[idx];
    }
    __syncthreads();

    if (isK) {
        union { s16x8 v; unsigned short u[8]; } t8;
        #pragma unroll
        for (int h = 0; h < 2; ++h) {
            const int f = wv * 2 + h;
            const int tt2 = f >> 2, s = f & 3;
            const float* p = &tl[(tt2 * 16 + n) * 132 + s * 32 + quad * 8];
            const float4 a = *(const float4*)p;
            const float4 c = *(const float4*)(p + 4);
            t8.u[0] = f2bf(a.x); t8.u[1] = f2bf(a.y); t8.u[2] = f2bf(a.z); t8.u[3] = f2bf(a.w);
            t8.u[4] = f2bf(c.x); t8.u[5] = f2bf(c.y); t8.u[6] = f2bf(c.z); t8.u[7] = f2bf(c.w);
            const int w = b * 256 + (kt * 2 + tt2) * 4 + s;
            *(s16x8*)(Kb + (size_t)w * 512 + lane * 8) = t8.v;
        }
    } else {
        #pragma unroll
        for (int h = 0; h < 2; ++h) {
            const int f  = wv * 2 + h;
            const int kg = f >> 2, dp = f & 3;
            f16x8 t8;
            #pragma unroll
            for (int i = 0; i < 4; ++i) {
                const float* row = &tl[(kg * 16 + quad * 4 + i) * 132 + dp * 32 + n];
                t8[i]     = (_Float16)row[0];
                t8[4 + i] = (_Float16)row[16];
            }
            const int v = (b * 64 + kt * 2 + kg) * 4 + dp;
            *(f16x8*)(Vt + (size_t)v * 512 + lane * 8) = t8;
        }
    }
}

// ---------------------------------------------------------------------------
// Attention v3: LDS-shared K/V chunks, QR=64, no split-K.
// MODEL (r0/r1 post-mortem): both prior versions sat on a ~9 TB/s VMEM
// request-path plateau; time tracked Kb/Vt bytes requested (r0: 312MB/34us,
// r1: 576MB/63us). Lever = request volume + request batching, NOT occupancy.
// STRUCTURE: block = 4 waves x 1 qtile = 64 q-rows. Each 64-kpos chunk
// (16KB Kb + 16KB Vt, contiguous in the prep layout) is DMA'd to LDS ONCE
// per block via global_load_lds dwordx4 (8 instr/thread, MLP=8), shared by
// all 4 waves -> Kb/Vt traffic halves vs r0 (~140MB). Double-buffered,
// 2-phase schedule (T3-minimum): STAGE(next) -> compute(cur) -> vmcnt(0) +
// raw s_barrier (NOT __syncthreads: that would drain the prefetch early;
// the asm "memory" clobber pins LDS-read ordering, sched_barrier(0) per
// guide rule #18). LDS 64KB -> 2 blocks/CU, 8 waves/CU (same occ as r0),
// ~60 VGPR/wave. No split-K -> no LDS merge, each wave owns its 16 rows.
// Register rule (r6-r8 failure): NEVER index a register array with a
// runtime value — all register indices are compile-time constants (LDS
// buffer index `cur` is fine: memory, not registers).
// Block swizzle: b's low 3 bits = blockIdx&7 (XCD affinity: 4 batches/XCD,
// Kb+Vt working set 1MB/XCD in L2); top 2 bits mix (idx>>3)+(idx>>8);
// bijective for the 512-block grid (qg = idx>>5 is untouched by the mix).
// Transposed-S trick unchanged: S^T = K.Q^T C-layout == A-operand layout of
// 16x16x16 f16 MFMA -> exp2(S^T) feeds PV directly.
// ---------------------------------------------------------------------------
__global__ __launch_bounds__(256)
void attn_fwd(const float* __restrict__ Q, const unsigned short* __restrict__ Kb,
              const _Float16* __restrict__ Vt, const int* __restrict__ VL,
              float* __restrict__ O)
{
    __shared__ __align__(16) unsigned short bufK[2][16 * 512];  // 16 KB / buf
    __shared__ __align__(16) _Float16       bufV[2][16 * 512];  // 16 KB / buf

    const int tid  = threadIdx.x;
    const int lane = tid & 63;
    const int w    = tid >> 6;     // wave id == qtile id (16 q-rows each)
    const int quad = lane >> 4;
    const int m16  = lane & 15;

    const int idx = blockIdx.x;
    const int qg  = (idx >> 5) & 15;
    const int b   = (idx & 7) | ((((idx >> 3) + (idx >> 8)) & 3) << 3);
    const int q0  = qg * 64;

    const int vl  = VL[b];
    const int nch = (vl > 0) ? ((vl + 63) >> 6) : 16;
    const float emaskval = (vl == 0) ? 1.0f : 0.0f;

    // Q fragments for this wave's qtile (B-operand of transposed QK^T)
    s16x8 qf[4];
    {
        const float* qrow = Q + ((size_t)b * LQ + q0 + w * 16 + m16) * DH + quad * 8;
        #pragma unroll
        for (int s = 0; s < 4; ++s) {
            const float4 a = *(const float4*)(qrow + s * 32);
            const float4 c = *(const float4*)(qrow + s * 32 + 4);
            union { s16x8 v; unsigned short u[8]; } t;
            t.u[0] = f2bf(a.x); t.u[1] = f2bf(a.y); t.u[2] = f2bf(a.z); t.u[3] = f2bf(a.w);
            t.u[4] = f2bf(c.x); t.u[5] = f2bf(c.y); t.u[6] = f2bf(c.z); t.u[7] = f2bf(c.w);
            qf[s] = t.v;
        }
    }

    f32x4 o[8];
    #pragma unroll
    for (int dt = 0; dt < 8; ++dt) o[dt] = (f32x4){0.f, 0.f, 0.f, 0.f};
    float lrun = 0.f;

    // chunk t occupies shorts [t*8192, (t+1)*8192) of this batch's Kb / Vt
    const unsigned short* kg0 = Kb + (size_t)b * (256 * 512);
    const _Float16*       vg0 = Vt + (size_t)b * (256 * 512);
    const int co = tid * 8;  // this thread's 16B slot within a 16KB chunk copy

    // STAGE(c, t): 8 x global_load_lds dwordx4 per thread (4 K + 4 V)
#define STAGE(c, t)                                                             \
    do {                                                                        \
        const unsigned short* gk_ = kg0 + (size_t)(t) * 8192;                   \
        const _Float16*       gv_ = vg0 + (size_t)(t) * 8192;                   \
        _Pragma("unroll")                                                       \
        for (int it_ = 0; it_ < 4; ++it_)                                       \
            G2L16(gk_ + it_ * 2048 + co, &bufK[c][it_ * 2048 + co]);            \
        _Pragma("unroll")                                                       \
        for (int it_ = 0; it_ < 4; ++it_)                                       \
            G2L16(gv_ + it_ * 2048 + co, &bufV[c][it_ * 2048 + co]);            \
    } while (0)

    // prologue: land chunk 0
    STAGE(0, 0);
    asm volatile("s_waitcnt vmcnt(0)" ::: "memory");
    __builtin_amdgcn_sched_barrier(0);
    __builtin_amdgcn_s_barrier();

    int cur = 0;
    for (int t = 0; t < nch; ++t) {
        if (t + 1 < nch) STAGE(cur ^ 1, t + 1);   // prefetch flies under compute

        const unsigned short* bk = &bufK[cur][0];
        const _Float16*       bv = &bufV[cur][0];
        const bool maskc = (t * 64 + 64 > vl);
        f16x4 pA[4];

        // ---- S^T = K Q^T per 16-kpos tile g, softmaxed immediately ----
        #pragma unroll
        for (int g = 0; g < 4; ++g) {
            f32x4 st = (f32x4){0.f, 0.f, 0.f, 0.f};
            #pragma unroll
            for (int s = 0; s < 4; ++s) {
                const s16x8 kf = *(const s16x8*)(bk + (g * 4 + s) * 512 + lane * 8);
                st = __builtin_amdgcn_mfma_f32_16x16x32_bf16(kf, qf[s], st, 0, 0, 0);
            }
            #pragma unroll
            for (int i = 0; i < 4; ++i) {
                float e = __builtin_amdgcn_exp2f(st[i] * ESCALE);
                if (maskc && (t * 64 + g * 16 + quad * 4 + i >= vl)) e = emaskval;
                lrun += e;
                pA[g][i] = (_Float16)e;
            }
        }

        // ---- O += P V : 4 kpos-tiles x 4 d-pairs ----
        #pragma unroll
        for (int g = 0; g < 4; ++g) {
            #pragma unroll
            for (int dp = 0; dp < 4; ++dp) {
                const f16x8 w8 = *(const f16x8*)(bv + (g * 4 + dp) * 512 + lane * 8);
                const f16x4 lo = __builtin_shufflevector(w8, w8, 0, 1, 2, 3);
                const f16x4 hi = __builtin_shufflevector(w8, w8, 4, 5, 6, 7);
                o[dp * 2]     = __builtin_amdgcn_mfma_f32_16x16x16f16(pA[g], lo, o[dp * 2],     0, 0, 0);
                o[dp * 2 + 1] = __builtin_amdgcn_mfma_f32_16x16x16f16(pA[g], hi, o[dp * 2 + 1], 0, 0, 0);
            }
        }

        // next buffer landed + everyone done reading cur -> safe to swap
        asm volatile("s_waitcnt vmcnt(0)" ::: "memory");
        __builtin_amdgcn_sched_barrier(0);
        __builtin_amdgcn_s_barrier();
        cur ^= 1;
    }
#undef STAGE

    // ---- epilogue: no split-K merge; wave owns its 16 rows outright ----
    float L = lrun;
    L += __shfl_xor(L, 16);
    L += __shfl_xor(L, 32);
    const size_t obase = ((size_t)b * LQ + q0 + w * 16 + quad * 4) * DH + m16;
    #pragma unroll
    for (int r = 0; r < 4; ++r) {
        const float inv = 1.0f / __shfl(L, quad * 4 + r);
        #pragma unroll
        for (int dt = 0; dt < 8; ++dt)
            O[obase + (size_t)r * DH + dt * 16] = o[dt][r] * inv;
    }
}

extern "C" void kernel_launch(void* const* d_in, const int* in_sizes, int n_in,
                              void* d_out, int out_size, void* d_ws, size_t ws_size,
                              hipStream_t stream) {
    const float* Q  = (const float*)d_in[0];
    const float* K  = (const float*)d_in[1];
    const float* V  = (const float*)d_in[2];
    const int*   VL = (const int*)d_in[3];
    float* O = (float*)d_out;
    (void)in_sizes; (void)n_in; (void)out_size; (void)ws_size;

    unsigned short* Kb = (unsigned short*)d_ws;                      // 8 MB K fragments
    _Float16*       Vt = (_Float16*)(Kb + (size_t)B_N * 256 * 512);  // 8 MB V frag-pairs

    prep_kv<<<dim3(2048), dim3(256), 0, stream>>>(K, V, VL, Kb, Vt);
    attn_fwd<<<dim3(B_N * (LQ / 64)), dim3(256), 0, stream>>>(Q, Kb, Vt, VL, O);
}

// Round 3
// 115.296 us; speedup vs baseline: 1.2708x; 1.0048x over previous
//
#include <hip/hip_runtime.h>

#define B_N 32
#define LQ  1024
#define LK  1024
#define DH  128

typedef __attribute__((ext_vector_type(4))) float    f32x4;
typedef __attribute__((ext_vector_type(8))) short    s16x8;
typedef __attribute__((ext_vector_type(4))) _Float16 f16x4;
typedef __attribute__((ext_vector_type(8))) _Float16 f16x8;

// fp32 -> bf16 round-to-nearest-even
__device__ inline unsigned short f2bf(float f) {
    union { float f; unsigned u; } c; c.f = f;
    unsigned u = c.u;
    u += 0x7fffu + ((u >> 16) & 1u);
    return (unsigned short)(u >> 16);
}

// logit2 = score * (1/sqrt(128)) * log2(e)
#define ESCALE 0.12751743f

// async global->LDS, 16B per lane (dest must be wave-uniform base + lane*16)
#define G2L16(gp, lp) __builtin_amdgcn_global_load_lds(                         \
    (const __attribute__((address_space(1))) void*)(gp),                        \
    (__attribute__((address_space(3))) void*)(lp), 16, 0, 0)

// ---------------------------------------------------------------------------
// Prepass, XCD-ALIGNED (the round-3 change — everything else byte-identical).
// r0-r2 post-mortem: all attn variants plateaued at ~5 TB/s fragment reads.
// Cause: prep's default blockIdx decode scattered batch b's Kb/Vt across all
// 8 XCD L2s while attn pins batch b's readers to XCD b&7 -> 7/8 of reads
// crossed the XCD/L3 path. Fix: decode so idx&7 == b&7 (same XCD as the
// attn consumers, assuming round-robin blockIdx->XCD dispatch — the same
// assumption attn's swizzle already makes). Bijective over 2048 blocks:
//   b = (idx&7) | ((idx>>3 & 3)<<3), kt = idx>>5 & 31, isK = idx>>10.
// Per XCD: 4 batches x 512 KB = 2 MB of fragments, fits 4 MB L2.
// vl-aware skip unchanged (~46% of tiles never read by attn).
// ---------------------------------------------------------------------------
__global__ __launch_bounds__(256)
void prep_kv(const float* __restrict__ K, const float* __restrict__ V,
             const int* __restrict__ VL,
             unsigned short* __restrict__ Kb, _Float16* __restrict__ Vt)
{
    __shared__ float tl[32 * 132];
    const int tid  = threadIdx.x;
    const int lane = tid & 63;
    const int wv   = tid >> 6;
    const int n    = lane & 15;
    const int quad = lane >> 4;

    const int  idx = blockIdx.x;
    const bool isK = (idx >> 10) == 0;
    const int  b   = (idx & 7) | (((idx >> 3) & 3) << 3);
    const int  kt  = (idx >> 5) & 31;

    const int vl = VL[b];
    if (isK) {
        if (vl <= 0 || kt >= 2 * ((vl + 63) >> 6)) return;   // block-uniform
    } else {
        const int nch = (vl > 0) ? ((vl + 63) >> 6) : 16;
        if (kt >= 2 * nch) return;                           // block-uniform
    }

    const float4* src = (const float4*)((isK ? K : V) + ((size_t)b * LK + kt * 32) * DH);
    #pragma unroll
    for (int h = 0; h < 4; ++h) {
        const int i2 = h * 256 + tid;
        const int row = i2 >> 5, c4 = i2 & 31;
        *(float4*)&tl[row * 132 + c4 * 4] = src[i2];
    }
    __syncthreads();

    if (isK) {
        union { s16x8 v; unsigned short u[8]; } t8;
        #pragma unroll
        for (int h = 0; h < 2; ++h) {
            const int f = wv * 2 + h;
            const int tt2 = f >> 2, s = f & 3;
            const float* p = &tl[(tt2 * 16 + n) * 132 + s * 32 + quad * 8];
            const float4 a = *(const float4*)p;
            const float4 c = *(const float4*)(p + 4);
            t8.u[0] = f2bf(a.x); t8.u[1] = f2bf(a.y); t8.u[2] = f2bf(a.z); t8.u[3] = f2bf(a.w);
            t8.u[4] = f2bf(c.x); t8.u[5] = f2bf(c.y); t8.u[6] = f2bf(c.z); t8.u[7] = f2bf(c.w);
            const int w = b * 256 + (kt * 2 + tt2) * 4 + s;
            *(s16x8*)(Kb + (size_t)w * 512 + lane * 8) = t8.v;
        }
    } else {
        #pragma unroll
        for (int h = 0; h < 2; ++h) {
            const int f  = wv * 2 + h;
            const int kg = f >> 2, dp = f & 3;
            f16x8 t8;
            #pragma unroll
            for (int i = 0; i < 4; ++i) {
                const float* row = &tl[(kg * 16 + quad * 4 + i) * 132 + dp * 32 + n];
                t8[i]     = (_Float16)row[0];
                t8[4 + i] = (_Float16)row[16];
            }
            const int v = (b * 64 + kt * 2 + kg) * 4 + dp;
            *(f16x8*)(Vt + (size_t)v * 512 + lane * 8) = t8;
        }
    }
}

// ---------------------------------------------------------------------------
// Attention v3 (UNCHANGED from round 2): LDS-shared K/V chunks, QR=64,
// no split-K. Block = 4 waves x 1 qtile = 64 q-rows; each 64-kpos chunk
// (16KB Kb + 16KB Vt) DMA'd to LDS once per block via global_load_lds
// dwordx4, double-buffered 2-phase: STAGE(next) -> compute(cur) ->
// vmcnt(0) + raw s_barrier (sched_barrier(0) per guide rule #18).
// LDS 64KB -> 2 blocks/CU, 8 waves/CU, ~52 VGPR/wave.
// Register rule: never index a register array with a runtime value (LDS
// buffer index `cur` is memory, fine).
// Block swizzle: b's low 3 bits = blockIdx&7 (XCD affinity — now actually
// honored by prep's aligned writes); top 2 bits mix (idx>>3)+(idx>>8) so
// the stride-256 CU pair gets different batches. Bijective per 32-group.
// Transposed-S trick: S^T = K.Q^T C-layout == A-operand layout of
// 16x16x16 f16 MFMA -> exp2(S^T) feeds PV directly.
// ---------------------------------------------------------------------------
__global__ __launch_bounds__(256)
void attn_fwd(const float* __restrict__ Q, const unsigned short* __restrict__ Kb,
              const _Float16* __restrict__ Vt, const int* __restrict__ VL,
              float* __restrict__ O)
{
    __shared__ __align__(16) unsigned short bufK[2][16 * 512];  // 16 KB / buf
    __shared__ __align__(16) _Float16       bufV[2][16 * 512];  // 16 KB / buf

    const int tid  = threadIdx.x;
    const int lane = tid & 63;
    const int w    = tid >> 6;     // wave id == qtile id (16 q-rows each)
    const int quad = lane >> 4;
    const int m16  = lane & 15;

    const int idx = blockIdx.x;
    const int qg  = (idx >> 5) & 15;
    const int b   = (idx & 7) | ((((idx >> 3) + (idx >> 8)) & 3) << 3);
    const int q0  = qg * 64;

    const int vl  = VL[b];
    const int nch = (vl > 0) ? ((vl + 63) >> 6) : 16;
    const float emaskval = (vl == 0) ? 1.0f : 0.0f;

    // Q fragments for this wave's qtile (B-operand of transposed QK^T)
    s16x8 qf[4];
    {
        const float* qrow = Q + ((size_t)b * LQ + q0 + w * 16 + m16) * DH + quad * 8;
        #pragma unroll
        for (int s = 0; s < 4; ++s) {
            const float4 a = *(const float4*)(qrow + s * 32);
            const float4 c = *(const float4*)(qrow + s * 32 + 4);
            union { s16x8 v; unsigned short u[8]; } t;
            t.u[0] = f2bf(a.x); t.u[1] = f2bf(a.y); t.u[2] = f2bf(a.z); t.u[3] = f2bf(a.w);
            t.u[4] = f2bf(c.x); t.u[5] = f2bf(c.y); t.u[6] = f2bf(c.z); t.u[7] = f2bf(c.w);
            qf[s] = t.v;
        }
    }

    f32x4 o[8];
    #pragma unroll
    for (int dt = 0; dt < 8; ++dt) o[dt] = (f32x4){0.f, 0.f, 0.f, 0.f};
    float lrun = 0.f;

    // chunk t occupies shorts [t*8192, (t+1)*8192) of this batch's Kb / Vt
    const unsigned short* kg0 = Kb + (size_t)b * (256 * 512);
    const _Float16*       vg0 = Vt + (size_t)b * (256 * 512);
    const int co = tid * 8;  // this thread's 16B slot within a 16KB chunk copy

    // STAGE(c, t): 8 x global_load_lds dwordx4 per thread (4 K + 4 V)
#define STAGE(c, t)                                                             \
    do {                                                                        \
        const unsigned short* gk_ = kg0 + (size_t)(t) * 8192;                   \
        const _Float16*       gv_ = vg0 + (size_t)(t) * 8192;                   \
        _Pragma("unroll")                                                       \
        for (int it_ = 0; it_ < 4; ++it_)                                       \
            G2L16(gk_ + it_ * 2048 + co, &bufK[c][it_ * 2048 + co]);            \
        _Pragma("unroll")                                                       \
        for (int it_ = 0; it_ < 4; ++it_)                                       \
            G2L16(gv_ + it_ * 2048 + co, &bufV[c][it_ * 2048 + co]);            \
    } while (0)

    // prologue: land chunk 0
    STAGE(0, 0);
    asm volatile("s_waitcnt vmcnt(0)" ::: "memory");
    __builtin_amdgcn_sched_barrier(0);
    __builtin_amdgcn_s_barrier();

    int cur = 0;
    for (int t = 0; t < nch; ++t) {
        if (t + 1 < nch) STAGE(cur ^ 1, t + 1);   // prefetch flies under compute

        const unsigned short* bk = &bufK[cur][0];
        const _Float16*       bv = &bufV[cur][0];
        const bool maskc = (t * 64 + 64 > vl);
        f16x4 pA[4];

        // ---- S^T = K Q^T per 16-kpos tile g, softmaxed immediately ----
        #pragma unroll
        for (int g = 0; g < 4; ++g) {
            f32x4 st = (f32x4){0.f, 0.f, 0.f, 0.f};
            #pragma unroll
            for (int s = 0; s < 4; ++s) {
                const s16x8 kf = *(const s16x8*)(bk + (g * 4 + s) * 512 + lane * 8);
                st = __builtin_amdgcn_mfma_f32_16x16x32_bf16(kf, qf[s], st, 0, 0, 0);
            }
            #pragma unroll
            for (int i = 0; i < 4; ++i) {
                float e = __builtin_amdgcn_exp2f(st[i] * ESCALE);
                if (maskc && (t * 64 + g * 16 + quad * 4 + i >= vl)) e = emaskval;
                lrun += e;
                pA[g][i] = (_Float16)e;
            }
        }

        // ---- O += P V : 4 kpos-tiles x 4 d-pairs ----
        #pragma unroll
        for (int g = 0; g < 4; ++g) {
            #pragma unroll
            for (int dp = 0; dp < 4; ++dp) {
                const f16x8 w8 = *(const f16x8*)(bv + (g * 4 + dp) * 512 + lane * 8);
                const f16x4 lo = __builtin_shufflevector(w8, w8, 0, 1, 2, 3);
                const f16x4 hi = __builtin_shufflevector(w8, w8, 4, 5, 6, 7);
                o[dp * 2]     = __builtin_amdgcn_mfma_f32_16x16x16f16(pA[g], lo, o[dp * 2],     0, 0, 0);
                o[dp * 2 + 1] = __builtin_amdgcn_mfma_f32_16x16x16f16(pA[g], hi, o[dp * 2 + 1], 0, 0, 0);
            }
        }

        // next buffer landed + everyone done reading cur -> safe to swap
        asm volatile("s_waitcnt vmcnt(0)" ::: "memory");
        __builtin_amdgcn_sched_barrier(0);
        __builtin_amdgcn_s_barrier();
        cur ^= 1;
    }
#undef STAGE

    // ---- epilogue: no split-K merge; wave owns its 16 rows outright ----
    float L = lrun;
    L += __shfl_xor(L, 16);
    L += __shfl_xor(L, 32);
    const size_t obase = ((size_t)b * LQ + q0 + w * 16 + quad * 4) * DH + m16;
    #pragma unroll
    for (int r = 0; r < 4; ++r) {
        const float inv = 1.0f / __shfl(L, quad * 4 + r);
        #pragma unroll
        for (int dt = 0; dt < 8; ++dt)
            O[obase + (size_t)r * DH + dt * 16] = o[dt][r] * inv;
    }
}

extern "C" void kernel_launch(void* const* d_in, const int* in_sizes, int n_in,
                              void* d_out, int out_size, void* d_ws, size_t ws_size,
                              hipStream_t stream) {
    const float* Q  = (const float*)d_in[0];
    const float* K  = (const float*)d_in[1];
    const float* V  = (const float*)d_in[2];
    const int*   VL = (const int*)d_in[3];
    float* O = (float*)d_out;
    (void)in_sizes; (void)n_in; (void)out_size; (void)ws_size;

    unsigned short* Kb = (unsigned short*)d_ws;                      // 8 MB K fragments
    _Float16*       Vt = (_Float16*)(Kb + (size_t)B_N * 256 * 512);  // 8 MB V frag-pairs

    prep_kv<<<dim3(2048), dim3(256), 0, stream>>>(K, V, VL, Kb, Vt);
    attn_fwd<<<dim3(B_N * (LQ / 64)), dim3(256), 0, stream>>>(Q, Kb, Vt, VL, O);
}